// Round 10
// baseline (205.563 us; speedup 1.0000x reference)
//
#include <hip/hip_runtime.h>
#include <stdint.h>

typedef _Float16 f16;
typedef __attribute__((ext_vector_type(8)))  _Float16 f16x8;
typedef __attribute__((ext_vector_type(4)))  float    f32x4;

#define NSTEPS 79
#define CDIM   256
#define ROWS   32                // rows per block (2 m-tiles of 16)
#define NKS    8                 // h k-steps (8 x K=32)
#define NT     4                 // n-tiles per wave -> 64 cols/wave
#define MTSZ   9216              // bytes per m-tile: 9 ksteps * 64 chunks * 16B
#define BUF    (2*MTSZ)          // one h buffer (2 m-tiles) = 18432 B

// ---------------------------------------------------------------------------
// R10: 4 waves x 64 cols (256 threads) -- halves the LDS all-to-all.
// Per-CU A-read traffic = waves x rows x K x 2B: 8 waves -> 144 KB (R9),
// 4 waves -> 72 KB. Same single-plane f16 h as R9 (absmax 0.0156 measured).
//
// 256 blocks x 256 threads (4 waves, 1 block/CU, 1 wave/SIMD).
// Wave w owns cols [w*64, w*64+64) (4 n-tiles) for all 32 rows (2 m-tiles).
// h: DOUBLE-BUFFERED, ONE barrier/step. FRAGMENT-MAJOR per m-tile:
//   off(mt,ks,dl,i) = mt*MTSZ + ks*1024 + swz(dl,ks)*16 + i*2
//   chunk dl holds A[m = dl&15][k = ks*32 + (dl>>4)*8 + i]
//   swz(dl,ks) = dl ^ ((dl>>3)&7) ^ (ks&7)
// value h[m][n]: ks=n>>5, kgroup=(n>>3)&3, i=n&7, dl=(m&15)+16*kgroup, mt=m>>4.
// kstep 8 = augmented x tile: A = [x_hi(k'0-3) | x_lo(k'4-7)],
//   Baug = [Wx_hi; Wx_hi] -> x_hi*Wx_hi + x_lo*Wx_hi (Wx_lo terms negligible).
// x prefetched from global each step.
//
// REGALLOC LAW (R1,R5-R8 measured): allocator grants cap/2 arch VGPRs:
// (256,1)->256, (512,2)->128, (512,4)->64; spills hard if demand exceeds it.
// Demand here ~217 <= 256 -> no spill. Spill signature: WRITE_SIZE >> 30MB.
// ---------------------------------------------------------------------------

// MFMA 16x16x32_f16 layout (verified R1):
//   A: lane l holds A[m = l&15][k = 8*(l>>4)+i]
//   B: lane l holds B[k = 8*(l>>4)+i][n = l&15]
//   C/D: lane l, reg r -> C[row = (l>>4)*4 + r][col = l&15]

__global__ __launch_bounds__(256, 1) void rnn_fused(
    const float* __restrict__ x0p, const float* __restrict__ x1p,
    const float* __restrict__ x2p, const float* __restrict__ x3p,
    const float* __restrict__ Wx,  const float* __restrict__ Wh,
    const float* __restrict__ brnn,const float* __restrict__ Wd,
    const float* __restrict__ bd,  float* __restrict__ out)
{
    __shared__ __align__(16) char hb[2*BUF];   // 36864 B (double-buffered h)

    const int tid  = (int)threadIdx.x;
    const int w    = tid >> 6;        // wave 0..3 -> cols [w*64, w*64+64)
    const int l    = tid & 63;
    const int ln16 = l & 15;
    const int kgl  = l >> 4;          // 0..3
    const int r0   = (int)blockIdx.x * ROWS;
    const int n0   = w * 64;

    // -------- Wh-hi fragments (4 n-tiles) + augmented Wx fragments --------
    f16x8 B1[NT][NKS];          // 128 VGPR; reused for Wd after the recurrence
    f16x8 Baug[NT];             // 16 VGPR
    float bias[NT];
    #pragma unroll
    for (int nt = 0; nt < NT; ++nt) {
        const int n = n0 + nt*16 + ln16;
        #pragma unroll
        for (int ks = 0; ks < NKS; ++ks) {
            const int k0 = ks*32 + kgl*8;
            f16x8 b;
            #pragma unroll
            for (int i = 0; i < 8; ++i)
                b[i] = (f16)Wh[(size_t)(k0 + i)*CDIM + n];
            B1[nt][ks] = b;
        }
        f16x8 e;
        #pragma unroll
        for (int i = 0; i < 8; ++i) e[i] = (f16)0.0f;
        if (kgl == 0) {
            // k' = i: rows 0-3 meet x_hi, rows 4-7 meet x_lo; both need Wx_hi
            #pragma unroll
            for (int i = 0; i < 4; ++i) {
                f16 whi = (f16)Wx[i*CDIM + n];
                e[i]   = whi;
                e[i+4] = whi;
            }
        }
        Baug[nt] = e;
        bias[nt] = brnn[n];
    }

    // -------- precomputed LDS addresses --------
    const unsigned rba = (unsigned)((l ^ ((l >> 3) & 7)) * 16);   // read base (within m-tile)
    int waddr[NT][4];   // write addr for (nt, r), m-tile 0; + MTSZ for m-tile 1
    #pragma unroll
    for (int nt = 0; nt < NT; ++nt) {
        const int n      = n0 + nt*16 + ln16;
        const int ksw    = n >> 5;
        const int kgroup = (n >> 3) & 3;
        const int i      = n & 7;
        #pragma unroll
        for (int r = 0; r < 4; ++r) {
            const int mr = kgl*4 + r;           // row within m-tile
            const int dl = mr + 16*kgroup;
            const int sw = dl ^ ((dl >> 3) & 7) ^ (ksw & 7);
            waddr[nt][r] = ksw*1024 + sw*16 + i*2;
        }
    }
    // x writer: tid<128 -> (row mfull = tid>>2, feature f = tid&3)
    const int  mfull = tid >> 2;
    const int  xf    = tid & 3;
    const int  xmt   = mfull >> 4;
    const int  xm    = mfull & 15;
    const int  xbase = xmt*MTSZ + NKS*1024 + (xm ^ ((xm >> 3) & 7))*16 + xf*2;
    const float* xptr = (xf == 0) ? x0p : (xf == 1) ? x1p : (xf == 2) ? x2p : x3p;
    const bool xwriter = (tid < 128);

    // -------- init: zero both buffers; write aug(0) into buffer 0 --------
    for (int i = tid; i < (2*BUF)/4; i += 256)
        ((uint32_t*)hb)[i] = 0u;
    float xv = 0.f;
    if (xwriter) xv = xptr[(size_t)(r0 + mfull)*NSTEPS + (NSTEPS - 1)];  // t=0 (reversed)
    __syncthreads();          // zeros done before aug write
    if (xwriter) {
        f16 hi = (f16)xv;
        f16 lo = (f16)(xv - (float)hi);
        *(f16*)(hb + xbase)     = hi;   // k' = xf     : x_hi
        *(f16*)(hb + xbase + 8) = lo;   // k' = 4 + xf : x_lo
    }
    __syncthreads();

    // -------- recurrence: ONE barrier per step (double-buffered) --------
    #pragma unroll 1
    for (int t = 0; t < NSTEPS; ++t) {
        const char* cbuf = hb + (t & 1)*BUF;
        char*       nbuf = hb + ((t + 1) & 1)*BUF;

        // prefetch next step's x early (latency hides under read+MFMA phase)
        float xnext = 0.f;
        if (xwriter && t + 1 < NSTEPS)
            xnext = xptr[(size_t)(r0 + mfull)*NSTEPS + (NSTEPS - 2 - t)];

        f32x4 acc[2][NT];
        #pragma unroll
        for (int mt = 0; mt < 2; ++mt)
        #pragma unroll
        for (int nt = 0; nt < NT; ++nt) {
            f32x4 vb = {bias[nt], bias[nt], bias[nt], bias[nt]};
            acc[mt][nt] = vb;
        }

        #pragma unroll
        for (int ks = 0; ks < NKS; ++ks) {
            const unsigned ra = (unsigned)(ks*1024) + (rba ^ (unsigned)((ks & 7) << 4));
            f16x8 a0 = *(const f16x8*)(cbuf + ra);            // m-tile 0
            f16x8 a1 = *(const f16x8*)(cbuf + MTSZ + ra);     // m-tile 1
            #pragma unroll
            for (int nt = 0; nt < NT; ++nt)
                acc[0][nt] = __builtin_amdgcn_mfma_f32_16x16x32_f16(a0, B1[nt][ks], acc[0][nt], 0, 0, 0);
            #pragma unroll
            for (int nt = 0; nt < NT; ++nt)
                acc[1][nt] = __builtin_amdgcn_mfma_f32_16x16x32_f16(a1, B1[nt][ks], acc[1][nt], 0, 0, 0);
        }
        {   // augmented x k-step (ks=8 -> ks&7=0, no xor term)
            const unsigned ra = (unsigned)(NKS*1024) + rba;
            f16x8 a0 = *(const f16x8*)(cbuf + ra);
            f16x8 a1 = *(const f16x8*)(cbuf + MTSZ + ra);
            #pragma unroll
            for (int nt = 0; nt < NT; ++nt)
                acc[0][nt] = __builtin_amdgcn_mfma_f32_16x16x32_f16(a0, Baug[nt], acc[0][nt], 0, 0, 0);
            #pragma unroll
            for (int nt = 0; nt < NT; ++nt)
                acc[1][nt] = __builtin_amdgcn_mfma_f32_16x16x32_f16(a1, Baug[nt], acc[1][nt], 0, 0, 0);
        }

        // writes go to the OTHER buffer -> no barrier needed before them
        if (xwriter && t + 1 < NSTEPS) {
            f16 hi = (f16)xnext;
            f16 lo = (f16)(xnext - (float)hi);
            *(f16*)(nbuf + xbase)     = hi;
            *(f16*)(nbuf + xbase + 8) = lo;
        }
        #pragma unroll
        for (int mt = 0; mt < 2; ++mt)
        #pragma unroll
        for (int nt = 0; nt < NT; ++nt) {
            #pragma unroll
            for (int r = 0; r < 4; ++r) {
                float v = acc[mt][nt][r];
                v = v > 0.f ? v : 0.f;
                *(f16*)(nbuf + waddr[nt][r] + mt*MTSZ) = (f16)v;
            }
        }
        __syncthreads();   // h(t+1)/aug(t+1) visible; cbuf free next step
    }

    // -------- final dense: out = relu(h @ Wd + b_d), reuse B1 regs --------
    // NSTEPS odd -> final h is in buffer 1
    #pragma unroll
    for (int nt = 0; nt < NT; ++nt) {
        const int n = n0 + nt*16 + ln16;
        #pragma unroll
        for (int ks = 0; ks < NKS; ++ks) {
            const int k0 = ks*32 + kgl*8;
            f16x8 b;
            #pragma unroll
            for (int i = 0; i < 8; ++i)
                b[i] = (f16)Wd[(size_t)(k0 + i)*CDIM + n];
            B1[nt][ks] = b;
        }
    }
    {
        const char* rp = hb + BUF;
        f32x4 acc[2][NT];
        #pragma unroll
        for (int mt = 0; mt < 2; ++mt)
        #pragma unroll
        for (int nt = 0; nt < NT; ++nt) {
            float b = bd[n0 + nt*16 + ln16];
            f32x4 vb = {b, b, b, b};
            acc[mt][nt] = vb;
        }
        #pragma unroll
        for (int ks = 0; ks < NKS; ++ks) {
            const unsigned ra = (unsigned)(ks*1024) + (rba ^ (unsigned)((ks & 7) << 4));
            f16x8 a0 = *(const f16x8*)(rp + ra);
            f16x8 a1 = *(const f16x8*)(rp + MTSZ + ra);
            #pragma unroll
            for (int nt = 0; nt < NT; ++nt)
                acc[0][nt] = __builtin_amdgcn_mfma_f32_16x16x32_f16(a0, B1[nt][ks], acc[0][nt], 0, 0, 0);
            #pragma unroll
            for (int nt = 0; nt < NT; ++nt)
                acc[1][nt] = __builtin_amdgcn_mfma_f32_16x16x32_f16(a1, B1[nt][ks], acc[1][nt], 0, 0, 0);
        }
        #pragma unroll
        for (int mt = 0; mt < 2; ++mt)
        #pragma unroll
        for (int nt = 0; nt < NT; ++nt) {
            const int n = n0 + nt*16 + ln16;
            #pragma unroll
            for (int r = 0; r < 4; ++r) {
                const int mr = mt*16 + kgl*4 + r;
                float v = acc[mt][nt][r];
                v = v > 0.f ? v : 0.f;
                out[(size_t)(r0 + mr)*CDIM + n] = v;
            }
        }
    }
}

extern "C" void kernel_launch(void* const* d_in, const int* in_sizes, int n_in,
                              void* d_out, int out_size, void* d_ws, size_t ws_size,
                              hipStream_t stream)
{
    (void)in_sizes; (void)n_in; (void)out_size; (void)d_ws; (void)ws_size;
    const float* x0 = (const float*)d_in[0];
    const float* x1 = (const float*)d_in[1];
    const float* x2 = (const float*)d_in[2];
    const float* x3 = (const float*)d_in[3];
    const float* Wx = (const float*)d_in[4];
    const float* Wh = (const float*)d_in[5];
    const float* br = (const float*)d_in[6];
    const float* Wd = (const float*)d_in[7];
    const float* bd = (const float*)d_in[8];
    float* out = (float*)d_out;

    rnn_fused<<<dim3(8192 / ROWS), dim3(256), 0, stream>>>(
        x0, x1, x2, x3, Wx, Wh, br, Wd, bd, out);
}